// Round 1
// baseline (348.942 us; speedup 1.0000x reference)
//
#include <hip/hip_runtime.h>
#include <math.h>

// GridNeRF fused hierarchical sampling + volume rendering.
// N=65536 rays, NC=64 coarse, NF=128 fine, S=192 combined samples.
// One wave (64 lanes) per ray; 4 rays per 256-thread block.
// Sort of 192 (+64 pad) t-values done as a 256-element bitonic network
// with 4 values/lane in registers and __shfl_xor cross-lane exchanges
// (avoids LDS-pipe-bound LDS bitonic: only xor-16/32 shuffles hit LDS HW).

#define NRAYS 65536
#define NCC   64
#define NFF   128
#define SS    192

__global__ __launch_bounds__(256)
void nerf_fused(const float* __restrict__ ro,  const float* __restrict__ rd,
                const float* __restrict__ cw,  const float* __restrict__ ct,
                const float* __restrict__ uu,  const float* __restrict__ col,
                const float* __restrict__ den, float* __restrict__ out)
{
    const int lane = threadIdx.x & 63;
    const int wv   = threadIdx.x >> 6;
    const int ray  = blockIdx.x * 4 + wv;

    __shared__ float s_cdf[4][66];    // cdf[0..64] per ray (+pad)
    __shared__ float s_vals[4][256];  // [0..63]=coarse_t, [64..191]=fine_t, [192..255]=pad

    // ---------- Phase 1: weights -> cdf (wave scan), coarse_t staged ----------
    float wt = cw[(size_t)ray * NCC + lane] + 1e-5f;
    float tc = ct[(size_t)ray * NCC + lane];
    float x = wt;
    #pragma unroll
    for (int off = 1; off < 64; off <<= 1) {
        float y = __shfl_up(x, off);
        if (lane >= off) x += y;
    }
    float total = __shfl(x, 63);
    s_cdf[wv][lane + 1] = x / total;      // cdf[lane+1]
    if (lane == 0) s_cdf[wv][0] = 0.0f;
    s_vals[wv][lane] = tc;
    s_vals[wv][192 + lane] = 1e30f;       // sort pad (> max t = 1000)
    __syncthreads();

    // ---------- Phase 2: searchsorted(right) + inverse-CDF interp ----------
    const float* cdfp = s_cdf[wv];
    const float* tcp  = s_vals[wv];
    float2 u2 = *(const float2*)(uu + (size_t)ray * NFF + 2 * lane);
    float fr[2];
    #pragma unroll
    for (int q = 0; q < 2; ++q) {
        float u = q ? u2.y : u2.x;
        // cdf[0]=0 <= u always; find pos = max{j in [0,63]: cdf[j] <= u}; idx = pos+1
        int pos = 0;
        #pragma unroll
        for (int st = 32; st >= 1; st >>= 1) {
            int np = pos + st;                 // np in [1,63]
            pos = (cdfp[np] <= u) ? np : pos;
        }
        int below = pos;                       // == clip(idx-1, 0, 63)
        int above = (pos + 1 < 63) ? (pos + 1) : 63;  // == clip(idx, 0, 63)
        float cb = cdfp[below];
        float ca = cdfp[above];
        float tb = tcp[below];
        float ta = tcp[above];
        float dnm = ca - cb;
        dnm = (dnm < 1e-5f) ? 1.0f : dnm;
        float tt = (u - cb) / dnm;
        fr[q] = tb + tt * (ta - tb);
    }
    *(float2*)&s_vals[wv][NCC + 2 * lane] = make_float2(fr[0], fr[1]);
    __syncthreads();

    // ---------- Phase 3: bitonic sort of 256 (4 regs/lane, shfl_xor) ----------
    float4 vv4 = *(const float4*)&s_vals[wv][4 * lane];
    float v[4] = {vv4.x, vv4.y, vv4.z, vv4.w};
    #pragma unroll
    for (int k = 2; k <= 256; k <<= 1) {
        #pragma unroll
        for (int j = k >> 1; j >= 1; j >>= 1) {
            if (j >= 4) {
                const int m = j >> 2;                 // partner-lane xor mask
                bool lower = (lane & m) == 0;
                #pragma unroll
                for (int r = 0; r < 4; ++r) {
                    bool up = ((((lane << 2) | r) & k) == 0);
                    float p = __shfl_xor(v[r], m);
                    float mn = fminf(v[r], p), mx = fmaxf(v[r], p);
                    v[r] = (lower == up) ? mn : mx;
                }
            } else if (j == 2) {
                #pragma unroll
                for (int r = 0; r < 2; ++r) {
                    bool up = ((((lane << 2) | r) & k) == 0);
                    float a = v[r], b = v[r + 2];
                    v[r]     = up ? fminf(a, b) : fmaxf(a, b);
                    v[r + 2] = up ? fmaxf(a, b) : fminf(a, b);
                }
            } else { // j == 1
                #pragma unroll
                for (int r = 0; r < 4; r += 2) {
                    bool up = ((((lane << 2) | r) & k) == 0);
                    float a = v[r], b = v[r + 1];
                    v[r]     = up ? fminf(a, b) : fmaxf(a, b);
                    v[r + 1] = up ? fmaxf(a, b) : fminf(a, b);
                }
            }
        }
    }
    // lane l now owns sorted samples 4l..4l+3 (lanes 0..47 real, 48..63 pad)

    // ---------- Phase 4: volume rendering ----------
    float dx = rd[(size_t)ray * 3 + 0], dy = rd[(size_t)ray * 3 + 1], dz = rd[(size_t)ray * 3 + 2];
    float ox = ro[(size_t)ray * 3 + 0], oy = ro[(size_t)ray * 3 + 1], oz = ro[(size_t)ray * 3 + 2];
    float nrm = sqrtf(dx * dx + dy * dy + dz * dz);

    const bool active = lane < 48;
    float tnext = __shfl_down(v[0], 1);   // t[4(l+1)]
    float dd[4];
    dd[0] = v[1] - v[0];
    dd[1] = v[2] - v[1];
    dd[2] = v[3] - v[2];
    dd[3] = (lane == 47) ? 1e10f : (tnext - v[3]);

    float4 dn4 = make_float4(0.f, 0.f, 0.f, 0.f);
    if (active) dn4 = *(const float4*)(den + (size_t)ray * SS + 4 * lane);
    float dnv[4] = {dn4.x, dn4.y, dn4.z, dn4.w};

    float aa[4], ff[4];
    #pragma unroll
    for (int r = 0; r < 4; ++r) {
        float al = active ? (1.0f - expf(-dnv[r] * (dd[r] * nrm))) : 0.0f;
        aa[r] = al;
        ff[r] = active ? (1.0f - al + 1e-10f) : 1.0f;
    }

    // fine_points = origin + dir * t  (sorted order), 12 contiguous floats/lane
    if (active) {
        float* fp = out + (size_t)5 * NRAYS + (size_t)ray * (SS * 3) + 12 * lane;
        float4 p0 = make_float4(ox + dx * v[0], oy + dy * v[0], oz + dz * v[0], ox + dx * v[1]);
        float4 p1 = make_float4(oy + dy * v[1], oz + dz * v[1], ox + dx * v[2], oy + dy * v[2]);
        float4 p2 = make_float4(oz + dz * v[2], ox + dx * v[3], oy + dy * v[3], oz + dz * v[3]);
        *(float4*)(fp + 0) = p0;
        *(float4*)(fp + 4) = p1;
        *(float4*)(fp + 8) = p2;
    }

    // exclusive cumprod of ff over 192 samples: in-lane prefix + wave product-scan
    float pr1 = ff[0], pr2 = ff[0] * ff[1], pr3 = pr2 * ff[2];
    float lp = pr3 * ff[3];
    float sx = lp;
    #pragma unroll
    for (int off = 1; off < 64; off <<= 1) {
        float y = __shfl_up(sx, off);
        if (lane >= off) sx *= y;
    }
    float excl = __shfl_up(sx, 1);
    if (lane == 0) excl = 1.0f;
    float w0 = aa[0] * excl;
    float w1 = aa[1] * (excl * pr1);
    float w2 = aa[2] * (excl * pr2);
    float w3 = aa[3] * (excl * pr3);

    float4 c0 = make_float4(0.f,0.f,0.f,0.f), c1 = c0, c2 = c0;
    if (active) {
        const float* cp = col + (size_t)ray * (SS * 3) + 12 * lane;
        c0 = *(const float4*)(cp + 0);
        c1 = *(const float4*)(cp + 4);
        c2 = *(const float4*)(cp + 8);
    }
    float rr  = w0 * c0.x + w1 * c0.w + w2 * c1.z + w3 * c2.y;
    float gg  = w0 * c0.y + w1 * c1.x + w2 * c1.w + w3 * c2.z;
    float bb  = w0 * c0.z + w1 * c1.y + w2 * c2.x + w3 * c2.w;
    float dep = w0 * v[0] + w1 * v[1] + w2 * v[2] + w3 * v[3];
    float opa = w0 + w1 + w2 + w3;

    #pragma unroll
    for (int off = 32; off >= 1; off >>= 1) {
        rr  += __shfl_xor(rr,  off);
        gg  += __shfl_xor(gg,  off);
        bb  += __shfl_xor(bb,  off);
        dep += __shfl_xor(dep, off);
        opa += __shfl_xor(opa, off);
    }
    if (lane == 0) {
        out[(size_t)ray * 3 + 0] = rr;
        out[(size_t)ray * 3 + 1] = gg;
        out[(size_t)ray * 3 + 2] = bb;
        out[(size_t)3 * NRAYS + ray] = dep;
        out[(size_t)4 * NRAYS + ray] = opa;
    }
}

extern "C" void kernel_launch(void* const* d_in, const int* in_sizes, int n_in,
                              void* d_out, int out_size, void* d_ws, size_t ws_size,
                              hipStream_t stream) {
    const float* ro  = (const float*)d_in[0];
    const float* rd  = (const float*)d_in[1];
    const float* cw  = (const float*)d_in[2];
    const float* ct  = (const float*)d_in[3];
    const float* uu  = (const float*)d_in[4];
    const float* col = (const float*)d_in[5];
    const float* den = (const float*)d_in[6];
    float* out = (float*)d_out;
    (void)in_sizes; (void)n_in; (void)out_size; (void)d_ws; (void)ws_size;
    nerf_fused<<<NRAYS / 4, 256, 0, stream>>>(ro, rd, cw, ct, uu, col, den, out);
}

// Round 2
// 344.909 us; speedup vs baseline: 1.0117x; 1.0117x over previous
//
#include <hip/hip_runtime.h>
#include <math.h>

// GridNeRF fused hierarchical sampling + volume rendering.
// N=65536 rays, NC=64 coarse, NF=128 fine, S=192 combined samples.
// One wave (64 lanes) per ray; 4 rays per 256-thread block; no __syncthreads
// (all LDS is wave-private slices, program order within a wave suffices).
//
// Sort strategy (R2): combined sort == merge of two sorted lists.
//  - coarse_t is sorted by construction (stratified bins).
//  - sorting the 128 u's (bitonic, 2 regs/lane, 28 stages) makes fine_t
//    sorted, since fine_t = Finv(u) with Finv monotone.
//  - merge ranks from the CDF: rank(coarse i) = i + #{u < cdf[i]},
//    rank(fine j) = j + pos_j + 1  (pos_j = searchsorted bin, needed for the
//    interpolation anyway). Exact stable-merge bijection -> collision-free
//    LDS scatter materializes the sorted t array.
//  - cdf forced monotone via a max-scan so the bijection is exact under FP.

#define NRAYS 65536
#define NCC   64
#define NFF   128
#define SS    192

__global__ __launch_bounds__(256)
void nerf_fused(const float* __restrict__ ro,  const float* __restrict__ rd,
                const float* __restrict__ cw,  const float* __restrict__ ct,
                const float* __restrict__ uu,  const float* __restrict__ col,
                const float* __restrict__ den, float* __restrict__ out)
{
    const int lane = threadIdx.x & 63;
    const int wv   = threadIdx.x >> 6;
    const int ray  = blockIdx.x * 4 + wv;

    __shared__ float s_cdf[4][65];    // cdf[0..64] (monotone)
    __shared__ float s_ct [4][64];    // coarse t
    __shared__ float s_su [4][128];   // sorted u
    __shared__ float s_vals[4][256];  // scatter target: sorted combined t + pad

    // ---------- Phase 1: weights -> normalized monotone cdf ----------
    float wt = cw[(size_t)ray * NCC + lane] + 1e-5f;
    float tc = ct[(size_t)ray * NCC + lane];
    float x = wt;
    #pragma unroll
    for (int off = 1; off < 64; off <<= 1) {
        float y = __shfl_up(x, off);
        if (lane >= off) x += y;
    }
    float total = __shfl(x, 63);
    float cv = x / total;
    // max-scan: enforce non-decreasing cdf (rank-scatter bijection guard)
    #pragma unroll
    for (int off = 1; off < 64; off <<= 1) {
        float y = __shfl_up(cv, off);
        if (lane >= off) cv = fmaxf(cv, y);
    }
    s_cdf[wv][lane + 1] = cv;
    if (lane == 0) s_cdf[wv][0] = 0.0f;
    s_ct[wv][lane] = tc;

    // ---------- Phase 2: bitonic sort of the 128 u's (2 regs/lane) ----------
    float2 u2 = *(const float2*)(uu + (size_t)ray * NFF + 2 * lane);
    float v0 = u2.x, v1 = u2.y;   // elements 2*lane, 2*lane+1
    #pragma unroll
    for (int k = 2; k <= 128; k <<= 1) {
        #pragma unroll
        for (int j = k >> 1; j >= 1; j >>= 1) {
            bool up = (((lane << 1) & k) == 0);   // same for both regs (k>=2)
            if (j == 1) {
                float a = v0, b = v1;
                v0 = up ? fminf(a, b) : fmaxf(a, b);
                v1 = up ? fmaxf(a, b) : fminf(a, b);
            } else {
                int m = j >> 1;                   // partner-lane xor mask
                bool keepmin = (((lane & m) == 0) == up);
                float p0 = __shfl_xor(v0, m);
                float p1 = __shfl_xor(v1, m);
                v0 = keepmin ? fminf(v0, p0) : fmaxf(v0, p0);
                v1 = keepmin ? fminf(v1, p1) : fmaxf(v1, p1);
            }
        }
    }
    *(float2*)&s_su[wv][2 * lane] = make_float2(v0, v1);

    // ---------- Phase 3: fine t from sorted u + scatter by merge rank ----------
    const float* cdfp = s_cdf[wv];
    const float* ctp  = s_ct[wv];
    float us[2] = {v0, v1};
    #pragma unroll
    for (int q = 0; q < 2; ++q) {
        float u = us[q];
        // pos = max{j in [0,63]: cdf[j] <= u}  (branchless descent)
        int pos = 0;
        #pragma unroll
        for (int st = 32; st >= 1; st >>= 1) {
            int np = pos + st;                 // np in [1,63]
            pos = (cdfp[np] <= u) ? np : pos;
        }
        int above = (pos + 1 < 63) ? (pos + 1) : 63;
        float cb = cdfp[pos], ca = cdfp[above];
        float tb = ctp[pos],  ta = ctp[above];
        float dnm = ca - cb;
        dnm = (dnm < 1e-5f) ? 1.0f : dnm;
        float tt = (u - cb) / dnm;
        float fval = tb + tt * (ta - tb);
        int rank = 2 * lane + q + pos + 1;     // j + #{coarse <= u_j}
        s_vals[wv][rank] = fval;
    }

    // ---------- Phase 4: coarse merge rank + scatter ----------
    const float* sup = s_su[wv];
    float key = cdfp[lane];                    // cdf[i], i = lane
    int cnt = 0;                               // #{u < cdf[i]}
    #pragma unroll
    for (int st = 128; st >= 1; st >>= 1) {
        int np = cnt + st;
        bool ok = (np <= 128) && (sup[np - 1] < key);
        cnt = ok ? np : cnt;
    }
    s_vals[wv][lane + cnt] = tc;
    s_vals[wv][192 + lane] = 0.0f;             // pad (zeros: keeps sums NaN-free)

    // ---------- Phase 5: volume rendering ----------
    float4 sv = *(const float4*)&s_vals[wv][4 * lane];
    float v[4] = {sv.x, sv.y, sv.z, sv.w};     // sorted samples 4l..4l+3

    float dx = rd[(size_t)ray * 3 + 0], dy = rd[(size_t)ray * 3 + 1], dz = rd[(size_t)ray * 3 + 2];
    float ox = ro[(size_t)ray * 3 + 0], oy = ro[(size_t)ray * 3 + 1], oz = ro[(size_t)ray * 3 + 2];
    float nrm = sqrtf(dx * dx + dy * dy + dz * dz);

    const bool active = lane < 48;
    float tnext = __shfl_down(v[0], 1);        // t[4(l+1)] (lane48 pad=0, masked)
    float dd[4];
    dd[0] = v[1] - v[0];
    dd[1] = v[2] - v[1];
    dd[2] = v[3] - v[2];
    dd[3] = (lane == 47) ? 1e10f : (tnext - v[3]);

    float4 dn4 = make_float4(0.f, 0.f, 0.f, 0.f);
    if (active) dn4 = *(const float4*)(den + (size_t)ray * SS + 4 * lane);
    float dnv[4] = {dn4.x, dn4.y, dn4.z, dn4.w};

    float aa[4], ff[4];
    #pragma unroll
    for (int r = 0; r < 4; ++r) {
        float al = active ? (1.0f - expf(-dnv[r] * (dd[r] * nrm))) : 0.0f;
        aa[r] = al;
        ff[r] = active ? (1.0f - al + 1e-10f) : 1.0f;
    }

    // fine_points = origin + dir * t (sorted order): 12 contiguous floats/lane
    if (active) {
        float* fp = out + (size_t)5 * NRAYS + (size_t)ray * (SS * 3) + 12 * lane;
        float4 p0 = make_float4(ox + dx * v[0], oy + dy * v[0], oz + dz * v[0], ox + dx * v[1]);
        float4 p1 = make_float4(oy + dy * v[1], oz + dz * v[1], ox + dx * v[2], oy + dy * v[2]);
        float4 p2 = make_float4(oz + dz * v[2], ox + dx * v[3], oy + dy * v[3], oz + dz * v[3]);
        *(float4*)(fp + 0) = p0;
        *(float4*)(fp + 4) = p1;
        *(float4*)(fp + 8) = p2;
    }

    // exclusive cumprod of (1-alpha+1e-10) over 192: in-lane prefix + wave scan
    float pr1 = ff[0], pr2 = ff[0] * ff[1], pr3 = pr2 * ff[2];
    float sx = pr3 * ff[3];
    #pragma unroll
    for (int off = 1; off < 64; off <<= 1) {
        float y = __shfl_up(sx, off);
        if (lane >= off) sx *= y;
    }
    float excl = __shfl_up(sx, 1);
    if (lane == 0) excl = 1.0f;
    float w0 = aa[0] * excl;
    float w1 = aa[1] * (excl * pr1);
    float w2 = aa[2] * (excl * pr2);
    float w3 = aa[3] * (excl * pr3);

    float4 c0 = make_float4(0.f,0.f,0.f,0.f), c1 = c0, c2 = c0;
    if (active) {
        const float* cp = col + (size_t)ray * (SS * 3) + 12 * lane;
        c0 = *(const float4*)(cp + 0);
        c1 = *(const float4*)(cp + 4);
        c2 = *(const float4*)(cp + 8);
    }
    float rr  = w0 * c0.x + w1 * c0.w + w2 * c1.z + w3 * c2.y;
    float gg  = w0 * c0.y + w1 * c1.x + w2 * c1.w + w3 * c2.z;
    float bb  = w0 * c0.z + w1 * c1.y + w2 * c2.x + w3 * c2.w;
    float dep = w0 * v[0] + w1 * v[1] + w2 * v[2] + w3 * v[3];
    float opa = w0 + w1 + w2 + w3;

    #pragma unroll
    for (int off = 32; off >= 1; off >>= 1) {
        rr  += __shfl_xor(rr,  off);
        gg  += __shfl_xor(gg,  off);
        bb  += __shfl_xor(bb,  off);
        dep += __shfl_xor(dep, off);
        opa += __shfl_xor(opa, off);
    }
    if (lane == 0) {
        out[(size_t)ray * 3 + 0] = rr;
        out[(size_t)ray * 3 + 1] = gg;
        out[(size_t)ray * 3 + 2] = bb;
        out[(size_t)3 * NRAYS + ray] = dep;
        out[(size_t)4 * NRAYS + ray] = opa;
    }
}

extern "C" void kernel_launch(void* const* d_in, const int* in_sizes, int n_in,
                              void* d_out, int out_size, void* d_ws, size_t ws_size,
                              hipStream_t stream) {
    const float* ro  = (const float*)d_in[0];
    const float* rd  = (const float*)d_in[1];
    const float* cw  = (const float*)d_in[2];
    const float* ct  = (const float*)d_in[3];
    const float* uu  = (const float*)d_in[4];
    const float* col = (const float*)d_in[5];
    const float* den = (const float*)d_in[6];
    float* out = (float*)d_out;
    (void)in_sizes; (void)n_in; (void)out_size; (void)d_ws; (void)ws_size;
    nerf_fused<<<NRAYS / 4, 256, 0, stream>>>(ro, rd, cw, ct, uu, col, den, out);
}